// Round 6
// baseline (75.250 us; speedup 1.0000x reference)
//
#include <hip/hip_runtime.h>
#include <hip/hip_bf16.h>
#include <cmath>

#define BATCH  4
#define CDIM   64
#define CK     8
#define NSEQ   4096
#define NSPLIT 8
#define MT     128                    // m per block: 4 waves x 32
#define NT     128                    // n per staged h tile
#define NCHUNK (NSEQ / NSPLIT)        // 512 n per block
#define ITERS  (NCHUNK / NT)          // 4
#define HSTR   132                    // s_h row stride in shorts (264B, b64 2-way-free)
#define HBUFSZ (CDIM * HSTR)
#define LOG2E  1.4426950408889634f

typedef __attribute__((ext_vector_type(8)))  short short8;
typedef __attribute__((ext_vector_type(16))) float f32x16;

__device__ inline unsigned short f2bf(float f) {
    union { float f; unsigned u; } v; v.f = f;
    unsigned r = v.u + 0x7fff + ((v.u >> 16) & 1);   // RNE
    return (unsigned short)(r >> 16);
}
__device__ inline float bf2f(unsigned short h) {
    union { unsigned u; float f; } v; v.u = ((unsigned)h) << 16;
    return v.f;
}

// -------------------------------------------------------------------------
// Kernel 1: f = wq@x, g = wk@x (pre-scaled by log2e), h = wv@x.
// 512 blocks x 256 threads; block = 32 n of one batch; lane octet o = c-group.
// f_pair/g_pair[B][N][16] bf16 {hi x8 | lo x8}; h_bf[B][C][N] bf16.
// -------------------------------------------------------------------------
__global__ __launch_bounds__(256) void fgh_kernel(
    const float* __restrict__ x,  const float* __restrict__ wq,
    const float* __restrict__ wk, const float* __restrict__ wv,
    unsigned short* __restrict__ f_pair, unsigned short* __restrict__ g_pair,
    unsigned short* __restrict__ h_bf)
{
    __shared__ __align__(16) float s_wq[CDIM][CK];
    __shared__ __align__(16) float s_wk[CDIM][CK];
    __shared__ __align__(16) float s_wv[CDIM][68];

    const int t = threadIdx.x;
    #pragma unroll
    for (int u = 0; u < 2; ++u) {
        const int i = t + u * 256;
        const int k = i >> 6, c = i & 63;
        s_wq[c][k] = wq[i];
        s_wk[c][k] = wk[i];
    }
    #pragma unroll
    for (int u = 0; u < 16; ++u) {
        const int i = t + u * 256;
        const int d = i >> 6, c = i & 63;
        s_wv[c][d] = wv[i];
    }
    __syncthreads();

    const int b  = blockIdx.x >> 7;
    const int n0 = (blockIdx.x & 127) * 32;
    const int nl = t >> 3;               // 0..31
    const int o  = t & 7;                // c-octet
    const int n  = n0 + nl;

    float fa[CK]   = {0.f};
    float ga[CK]   = {0.f};
    float ha[CDIM] = {0.f};

    #pragma unroll
    for (int ci = 0; ci < 8; ++ci) {
        const int c   = o * 8 + ci;
        const float xv = x[(b * CDIM + c) * NSEQ + n];

        const float4 q0 = *(const float4*)&s_wq[c][0];
        const float4 q1 = *(const float4*)&s_wq[c][4];
        fa[0] += q0.x * xv; fa[1] += q0.y * xv; fa[2] += q0.z * xv; fa[3] += q0.w * xv;
        fa[4] += q1.x * xv; fa[5] += q1.y * xv; fa[6] += q1.z * xv; fa[7] += q1.w * xv;

        const float4 k0  = *(const float4*)&s_wk[c][0];
        const float4 k1v = *(const float4*)&s_wk[c][4];
        ga[0] += k0.x * xv; ga[1] += k0.y * xv; ga[2] += k0.z * xv; ga[3] += k0.w * xv;
        ga[4] += k1v.x * xv; ga[5] += k1v.y * xv; ga[6] += k1v.z * xv; ga[7] += k1v.w * xv;

        #pragma unroll
        for (int u = 0; u < 16; ++u) {
            const float4 v = *(const float4*)&s_wv[c][u * 4];
            ha[u*4+0] += v.x * xv; ha[u*4+1] += v.y * xv;
            ha[u*4+2] += v.z * xv; ha[u*4+3] += v.w * xv;
        }
    }

    // reduce across the 8-lane c-octet group
    #pragma unroll
    for (int k = 0; k < CK; ++k) {
        fa[k] += __shfl_xor(fa[k], 1); fa[k] += __shfl_xor(fa[k], 2); fa[k] += __shfl_xor(fa[k], 4);
        ga[k] += __shfl_xor(ga[k], 1); ga[k] += __shfl_xor(ga[k], 2); ga[k] += __shfl_xor(ga[k], 4);
    }
    #pragma unroll
    for (int d = 0; d < CDIM; ++d) {
        ha[d] += __shfl_xor(ha[d], 1); ha[d] += __shfl_xor(ha[d], 2); ha[d] += __shfl_xor(ha[d], 4);
    }

    if (o == 0) {
        unsigned short buf[16];
        #pragma unroll
        for (int k = 0; k < CK; ++k) {
            buf[k]     = f2bf(fa[k]);
            buf[8 + k] = f2bf(fa[k] - bf2f(buf[k]));
        }
        uint4* dst = (uint4*)&f_pair[(size_t)(b * NSEQ + n) * 16];
        dst[0] = ((const uint4*)buf)[0];
        dst[1] = ((const uint4*)buf)[1];
    }
    if (o == 1) {
        unsigned short buf[16];
        #pragma unroll
        for (int k = 0; k < CK; ++k) {
            const float gs = ga[k] * LOG2E;          // fold log2e into scores
            buf[k]     = f2bf(gs);
            buf[8 + k] = f2bf(gs - bf2f(buf[k]));
        }
        uint4* dst = (uint4*)&g_pair[(size_t)(b * NSEQ + n) * 16];
        dst[0] = ((const uint4*)buf)[0];
        dst[1] = ((const uint4*)buf)[1];
    }
    #pragma unroll
    for (int d = 0; d < CDIM; ++d) {
        if ((d >> 3) == o) h_bf[(size_t)(b * CDIM + d) * NSEQ + n] = f2bf(ha[d]);
    }
}

// -------------------------------------------------------------------------
// Kernel 2: all-MFMA flash attention. Double-buffered s_h (ONE barrier per
// tile), 2-deep score-MFMA pipeline ahead of exp/PV, T14 reg-staged h,
// T12 permlane P-exchange, raw v_exp_f32, setprio around PV, bf16 partials.
// -------------------------------------------------------------------------
__global__ __launch_bounds__(256, 4) void attn_kernel(
    const unsigned short* __restrict__ f_pair,
    const unsigned short* __restrict__ g_pair,
    const unsigned short* __restrict__ h_bf,
    unsigned short* __restrict__ o_part, float* __restrict__ l_part)
{
    __shared__ __align__(16) unsigned short s_h[2 * HBUFSZ];

    const int t    = threadIdx.x;
    const int lane = t & 63;
    const int w    = t >> 6;
    const int hh   = lane >> 5;
    const int lm   = lane & 31;

    const int bid = blockIdx.x;          // 1024 = s(8) * mt(32) * b(4)
    const int s   = bid & (NSPLIT - 1);
    const int mt  = (bid >> 3) & 31;
    const int b   = bid >> 8;

    const int m = mt * MT + w * 32 + lm;

    union U4 { short8 v; uint4 q4; unsigned u[4]; };

    U4 Bgh, Bgl;
    {
        const uint4* gp = (const uint4*)&g_pair[(size_t)(b * NSEQ + m) * 16];
        Bgh.q4 = gp[0];
        Bgl.q4 = gp[1];
    }

    f32x16 acc0 = {}, acc1 = {};
    const f32x16 kZero = {};
    float lsA = 0.f, lsB = 0.f;

    const unsigned short* fp = f_pair + (size_t)b * NSEQ * 16;
    const unsigned short* hb = h_bf  + (size_t)b * CDIM * NSEQ;
    const int base = s * NCHUNK;

    const int c_lo  = t >> 4;
    const int ng_st = t & 15;
    const unsigned short* fpl = fp + (size_t)lm * 16 + hh * 8;
    const unsigned short* hbl = hb + (size_t)c_lo * NSEQ + ng_st * 8;
    const int shw  = c_lo * HSTR + ng_st * 8;
    const int shrA = lm * HSTR;
    const int shrB = (32 + lm) * HSTR;

    auto issueH = [&](int n0, uint4 (&hr)[4]) {
        #pragma unroll
        for (int u = 0; u < 4; ++u)
            hr[u] = *(const uint4*)&hbl[(size_t)u * 16 * NSEQ + n0];
    };
    auto writeH = [&](int sel, const uint4 (&hr)[4]) {
        unsigned short* dst = &s_h[sel * HBUFSZ];
        #pragma unroll
        for (int u = 0; u < 4; ++u) {
            *(uint2*)&dst[shw + u * 16 * HSTR]     = make_uint2(hr[u].x, hr[u].y);
            *(uint2*)&dst[shw + u * 16 * HSTR + 4] = make_uint2(hr[u].z, hr[u].w);
        }
    };
    auto issueAf = [&](int n0, short8 (&af)[4]) {
        const unsigned short* p = fpl + (size_t)n0 * 16;
        #pragma unroll
        for (int sub = 0; sub < 4; ++sub)
            af[sub] = *(const short8*)&p[sub * 32 * 16];
    };
    auto scores = [&](const short8& a) -> f32x16 {
        f32x16 sc = __builtin_amdgcn_mfma_f32_32x32x16_bf16(a, Bgh.v, kZero, 0, 0, 0);
        return   __builtin_amdgcn_mfma_f32_32x32x16_bf16(a, Bgl.v, sc, 0, 0, 0);
    };
    auto pvstep = [&](const f32x16& sc, int sub, int sel) {
        unsigned a[8];
        #pragma unroll
        for (int p = 0; p < 8; ++p) {
            const float e0 = __builtin_amdgcn_exp2f(sc[2*p]);
            const float e1 = __builtin_amdgcn_exp2f(sc[2*p+1]);
            lsA += e0; lsB += e1;
            __hip_bfloat162 h2 = __float22bfloat162_rn(make_float2(e0, e1));
            a[p] = *(unsigned*)&h2;
        }
        const auto s02 = __builtin_amdgcn_permlane32_swap(a[0], a[2], false, false);
        const auto s13 = __builtin_amdgcn_permlane32_swap(a[1], a[3], false, false);
        const auto s46 = __builtin_amdgcn_permlane32_swap(a[4], a[6], false, false);
        const auto s57 = __builtin_amdgcn_permlane32_swap(a[5], a[7], false, false);

        U4 P0, P1;
        P0.u[0] = s02[0]; P0.u[1] = s13[0]; P0.u[2] = s02[1]; P0.u[3] = s13[1];
        P1.u[0] = s46[0]; P1.u[1] = s57[0]; P1.u[2] = s46[1]; P1.u[3] = s57[1];

        const unsigned short* src = &s_h[sel * HBUFSZ];
        union U2x { short8 v; uint2 q[2]; } Ah;
        __builtin_amdgcn_s_setprio(1);
        #pragma unroll
        for (int ks = 0; ks < 2; ++ks) {
            const int ko = sub * 32 + ks * 16 + hh * 8;
            const short8 Pv = ks ? P1.v : P0.v;
            Ah.q[0] = *(const uint2*)&src[shrA + ko];
            Ah.q[1] = *(const uint2*)&src[shrA + ko + 4];
            acc0 = __builtin_amdgcn_mfma_f32_32x32x16_bf16(Ah.v, Pv, acc0, 0, 0, 0);
            Ah.q[0] = *(const uint2*)&src[shrB + ko];
            Ah.q[1] = *(const uint2*)&src[shrB + ko + 4];
            acc1 = __builtin_amdgcn_mfma_f32_32x32x16_bf16(Ah.v, Pv, acc1, 0, 0, 0);
        }
        __builtin_amdgcn_s_setprio(0);
    };

    uint4  hrA[4], hrB[4];
    short8 afA[4], afB[4];

    // prologue: tile0 -> buf0 (visible after first barrier), tile1 in regs
    issueH(base, hrA);
    writeH(0, hrA);
    issueAf(base, afA);
    if (ITERS > 1) issueH(base + NT, hrB);

    #pragma unroll
    for (int it = 0; it < ITERS; ++it) {
        const int sel = it & 1;
        __syncthreads();   // buf[sel] written pre-barrier is now visible;
                           // all waves are done reading buf[sel^1] (tile it-1)
        if (it + 1 < ITERS) {
            if (sel) writeH(sel ^ 1, hrA); else writeH(sel ^ 1, hrB);   // tile it+1
        }
        if (it + 2 < ITERS) {
            if (sel) issueH(base + (it + 2) * NT, hrB);
            else     issueH(base + (it + 2) * NT, hrA);                 // tile it+2
        }
        if (it + 1 < ITERS) {
            if (sel) issueAf(base + (it + 1) * NT, afA);
            else     issueAf(base + (it + 1) * NT, afB);                // f tile it+1
        }
        const short8 (&af)[4] = sel ? afB : afA;
        // 2-deep score pipeline: next sub's score MFMAs in flight during exp/PV
        f32x16 s0 = scores(af[0]);
        f32x16 s1 = scores(af[1]);
        pvstep(s0, 0, sel);
        f32x16 s2 = scores(af[2]);
        pvstep(s1, 1, sel);
        f32x16 s3 = scores(af[3]);
        pvstep(s2, 2, sel);
        pvstep(s3, 3, sel);
    }

    const float lsum = lsA + lsB;
    const float ltot = lsum + __shfl_xor(lsum, 32);
    if (hh == 0) l_part[(s * BATCH + b) * NSEQ + m] = ltot;

    unsigned short* ob = o_part + (size_t)(s * BATCH + b) * CDIM * NSEQ;
    #pragma unroll
    for (int r = 0; r < 16; ++r) {
        const int c0 = (r & 3) + 8 * (r >> 2) + 4 * hh;
        ob[(size_t)c0 * NSEQ + m]        = f2bf(acc0[r]);
        ob[(size_t)(32 + c0) * NSEQ + m] = f2bf(acc1[r]);
    }
}

// -------------------------------------------------------------------------
// Kernel 3: out = gamma * (sum_s o_part) / (sum_s l_part) + x
// -------------------------------------------------------------------------
__global__ __launch_bounds__(256) void final_kernel(
    const float* __restrict__ x, const unsigned short* __restrict__ o_part,
    const float* __restrict__ l_part, const float* __restrict__ gamma,
    float* __restrict__ out)
{
    const int i = blockIdx.x * 256 + threadIdx.x;      // 1M elements
    const int m = i & (NSEQ - 1);
    const int b = i >> 18;
    float o = 0.f, l = 0.f;
    #pragma unroll
    for (int s = 0; s < NSPLIT; ++s) {
        o += bf2f(o_part[(size_t)s * (BATCH * CDIM * NSEQ) + i]);
        l += l_part[s * (BATCH * NSEQ) + b * NSEQ + m];
    }
    out[i] = gamma[0] * o / l + x[i];
}

extern "C" void kernel_launch(void* const* d_in, const int* in_sizes, int n_in,
                              void* d_out, int out_size, void* d_ws, size_t ws_size,
                              hipStream_t stream) {
    const float* x     = (const float*)d_in[0];
    const float* wq    = (const float*)d_in[1];
    const float* wk    = (const float*)d_in[2];
    const float* wv    = (const float*)d_in[3];
    const float* gamma = (const float*)d_in[4];
    float* out = (float*)d_out;

    char* wsb = (char*)d_ws;
    unsigned short* f_pair = (unsigned short*)wsb;                         // 512 KB
    unsigned short* g_pair = f_pair + (size_t)BATCH * NSEQ * 16;           // 512 KB
    unsigned short* h_bf   = g_pair + (size_t)BATCH * NSEQ * 16;           // 2 MB
    unsigned short* o_part = (unsigned short*)(wsb + 3u * 1024 * 1024);    // 16 MB (bf16)
    float* l_part = (float*)(wsb + 19u * 1024 * 1024);                     // 512 KB

    hipLaunchKernelGGL(fgh_kernel, dim3(2 * BATCH * 64), dim3(256), 0, stream,
                       x, wq, wk, wv, f_pair, g_pair, h_bf);
    hipLaunchKernelGGL(attn_kernel, dim3(BATCH * 32 * NSPLIT), dim3(256), 0, stream,
                       f_pair, g_pair, h_bf, o_part, l_part);
    hipLaunchKernelGGL(final_kernel, dim3((BATCH * CDIM * NSEQ) / 256), dim3(256), 0, stream,
                       x, o_part, l_part, gamma, out);
}

// Round 7
// 48.089 us; speedup vs baseline: 1.5648x; 1.5648x over previous
//
#include <hip/hip_runtime.h>
#include <hip/hip_bf16.h>
#include <cmath>

#define BATCH  4
#define CDIM   64
#define CK     8
#define NSEQ   4096
#define NSPLIT 8
#define MT     128                    // m per block: 4 waves x 32
#define NT     128                    // n per staged h tile
#define NCHUNK (NSEQ / NSPLIT)        // 512 n per block
#define ITERS  (NCHUNK / NT)          // 4
#define HSTR   132                    // s_h row stride in shorts (264B, b64 2-way-free)
#define HBUFSZ (CDIM * HSTR)
#define LOG2E  1.4426950408889634f

typedef __attribute__((ext_vector_type(8)))  short short8;
typedef __attribute__((ext_vector_type(16))) float f32x16;

__device__ inline unsigned short f2bf(float f) {
    union { float f; unsigned u; } v; v.f = f;
    unsigned r = v.u + 0x7fff + ((v.u >> 16) & 1);   // RNE
    return (unsigned short)(r >> 16);
}
__device__ inline float bf2f(unsigned short h) {
    union { unsigned u; float f; } v; v.u = ((unsigned)h) << 16;
    return v.f;
}

// -------------------------------------------------------------------------
// Kernel 1: f = wq@x, g = wk@x (pre-scaled by log2e), h = wv@x.
// 256 blocks x 256 threads; quarter split q = t&3, c visited in ROTATED order
// c = 16q + ((ci+4q)&15) so concurrent LDS reads are 2-way (free), not 4/8-way.
// wq/wk rows padded to 12 floats (48B: b128-aligned + rotation-compatible).
// -------------------------------------------------------------------------
__global__ __launch_bounds__(256) void fgh_kernel(
    const float* __restrict__ x,  const float* __restrict__ wq,
    const float* __restrict__ wk, const float* __restrict__ wv,
    unsigned short* __restrict__ f_pair, unsigned short* __restrict__ g_pair,
    unsigned short* __restrict__ h_bf)
{
    __shared__ __align__(16) float s_wq[CDIM][12];   // 12-float rows: 2-way banks
    __shared__ __align__(16) float s_wk[CDIM][12];
    __shared__ __align__(16) float s_wv[CDIM][68];

    const int t = threadIdx.x;
    #pragma unroll
    for (int u = 0; u < 2; ++u) {
        const int i = t + u * 256;        // 512 = 8k x 64c
        const int k = i >> 6, c = i & 63;
        s_wq[c][k] = wq[i];
        s_wk[c][k] = wk[i];
    }
    #pragma unroll
    for (int u = 0; u < 16; ++u) {
        const int i = t + u * 256;        // 4096 = 64d x 64c
        const int d = i >> 6, c = i & 63;
        s_wv[c][d] = wv[i];
    }
    __syncthreads();

    const int b  = blockIdx.x >> 6;
    const int n0 = (blockIdx.x & 63) * 64;
    const int nl = t >> 2;
    const int q  = t & 3;
    const int n  = n0 + nl;

    float fa[CK]   = {0.f};
    float ga[CK]   = {0.f};
    float ha[CDIM] = {0.f};

    #pragma unroll
    for (int ci = 0; ci < 16; ++ci) {
        const int c   = q * 16 + ((ci + 4 * q) & 15);   // rotated visit order
        const float xv = x[(b * CDIM + c) * NSEQ + n];

        const float4 q0 = *(const float4*)&s_wq[c][0];
        const float4 q1 = *(const float4*)&s_wq[c][4];
        fa[0] += q0.x * xv; fa[1] += q0.y * xv; fa[2] += q0.z * xv; fa[3] += q0.w * xv;
        fa[4] += q1.x * xv; fa[5] += q1.y * xv; fa[6] += q1.z * xv; fa[7] += q1.w * xv;

        const float4 k0  = *(const float4*)&s_wk[c][0];
        const float4 k1v = *(const float4*)&s_wk[c][4];
        ga[0] += k0.x * xv; ga[1] += k0.y * xv; ga[2] += k0.z * xv; ga[3] += k0.w * xv;
        ga[4] += k1v.x * xv; ga[5] += k1v.y * xv; ga[6] += k1v.z * xv; ga[7] += k1v.w * xv;

        #pragma unroll
        for (int u = 0; u < 16; ++u) {
            const float4 v = *(const float4*)&s_wv[c][u * 4];
            ha[u*4+0] += v.x * xv; ha[u*4+1] += v.y * xv;
            ha[u*4+2] += v.z * xv; ha[u*4+3] += v.w * xv;
        }
    }

    // reduce partial sums across the 4-lane c-quarter group
    #pragma unroll
    for (int k = 0; k < CK; ++k) {
        fa[k] += __shfl_xor(fa[k], 1); fa[k] += __shfl_xor(fa[k], 2);
        ga[k] += __shfl_xor(ga[k], 1); ga[k] += __shfl_xor(ga[k], 2);
    }
    #pragma unroll
    for (int d = 0; d < CDIM; ++d) {
        ha[d] += __shfl_xor(ha[d], 1); ha[d] += __shfl_xor(ha[d], 2);
    }

    if (q == 0) {
        unsigned short buf[16];
        #pragma unroll
        for (int k = 0; k < CK; ++k) {
            buf[k]     = f2bf(fa[k]);
            buf[8 + k] = f2bf(fa[k] - bf2f(buf[k]));
        }
        uint4* dst = (uint4*)&f_pair[(size_t)(b * NSEQ + n) * 16];
        dst[0] = ((const uint4*)buf)[0];
        dst[1] = ((const uint4*)buf)[1];
    }
    if (q == 1) {
        unsigned short buf[16];
        #pragma unroll
        for (int k = 0; k < CK; ++k) {
            const float gs = ga[k] * LOG2E;          // fold log2e into scores
            buf[k]     = f2bf(gs);
            buf[8 + k] = f2bf(gs - bf2f(buf[k]));
        }
        uint4* dst = (uint4*)&g_pair[(size_t)(b * NSEQ + n) * 16];
        dst[0] = ((const uint4*)buf)[0];
        dst[1] = ((const uint4*)buf)[1];
    }
    #pragma unroll
    for (int d = 0; d < CDIM; ++d) {
        if ((d >> 4) == q) h_bf[(size_t)(b * CDIM + d) * NSEQ + n] = f2bf(ha[d]);
    }
}

// -------------------------------------------------------------------------
// Kernel 2 (UNCHANGED from round 6): all-MFMA flash attention. Double-buffered
// s_h (one barrier per tile), 2-deep score pipeline, T14 reg-staged h,
// T12 permlane P-exchange, raw v_exp_f32, setprio around PV, bf16 partials.
// -------------------------------------------------------------------------
__global__ __launch_bounds__(256, 4) void attn_kernel(
    const unsigned short* __restrict__ f_pair,
    const unsigned short* __restrict__ g_pair,
    const unsigned short* __restrict__ h_bf,
    unsigned short* __restrict__ o_part, float* __restrict__ l_part)
{
    __shared__ __align__(16) unsigned short s_h[2 * HBUFSZ];

    const int t    = threadIdx.x;
    const int lane = t & 63;
    const int w    = t >> 6;
    const int hh   = lane >> 5;
    const int lm   = lane & 31;

    const int bid = blockIdx.x;          // 1024 = s(8) * mt(32) * b(4)
    const int s   = bid & (NSPLIT - 1);
    const int mt  = (bid >> 3) & 31;
    const int b   = bid >> 8;

    const int m = mt * MT + w * 32 + lm;

    union U4 { short8 v; uint4 q4; unsigned u[4]; };

    U4 Bgh, Bgl;
    {
        const uint4* gp = (const uint4*)&g_pair[(size_t)(b * NSEQ + m) * 16];
        Bgh.q4 = gp[0];
        Bgl.q4 = gp[1];
    }

    f32x16 acc0 = {}, acc1 = {};
    const f32x16 kZero = {};
    float lsA = 0.f, lsB = 0.f;

    const unsigned short* fp = f_pair + (size_t)b * NSEQ * 16;
    const unsigned short* hb = h_bf  + (size_t)b * CDIM * NSEQ;
    const int base = s * NCHUNK;

    const int c_lo  = t >> 4;
    const int ng_st = t & 15;
    const unsigned short* fpl = fp + (size_t)lm * 16 + hh * 8;
    const unsigned short* hbl = hb + (size_t)c_lo * NSEQ + ng_st * 8;
    const int shw  = c_lo * HSTR + ng_st * 8;
    const int shrA = lm * HSTR;
    const int shrB = (32 + lm) * HSTR;

    auto issueH = [&](int n0, uint4 (&hr)[4]) {
        #pragma unroll
        for (int u = 0; u < 4; ++u)
            hr[u] = *(const uint4*)&hbl[(size_t)u * 16 * NSEQ + n0];
    };
    auto writeH = [&](int sel, const uint4 (&hr)[4]) {
        unsigned short* dst = &s_h[sel * HBUFSZ];
        #pragma unroll
        for (int u = 0; u < 4; ++u) {
            *(uint2*)&dst[shw + u * 16 * HSTR]     = make_uint2(hr[u].x, hr[u].y);
            *(uint2*)&dst[shw + u * 16 * HSTR + 4] = make_uint2(hr[u].z, hr[u].w);
        }
    };
    auto issueAf = [&](int n0, short8 (&af)[4]) {
        const unsigned short* p = fpl + (size_t)n0 * 16;
        #pragma unroll
        for (int sub = 0; sub < 4; ++sub)
            af[sub] = *(const short8*)&p[sub * 32 * 16];
    };
    auto scores = [&](const short8& a) -> f32x16 {
        f32x16 sc = __builtin_amdgcn_mfma_f32_32x32x16_bf16(a, Bgh.v, kZero, 0, 0, 0);
        return   __builtin_amdgcn_mfma_f32_32x32x16_bf16(a, Bgl.v, sc, 0, 0, 0);
    };
    auto pvstep = [&](const f32x16& sc, int sub, int sel) {
        unsigned a[8];
        #pragma unroll
        for (int p = 0; p < 8; ++p) {
            const float e0 = __builtin_amdgcn_exp2f(sc[2*p]);
            const float e1 = __builtin_amdgcn_exp2f(sc[2*p+1]);
            lsA += e0; lsB += e1;
            __hip_bfloat162 h2 = __float22bfloat162_rn(make_float2(e0, e1));
            a[p] = *(unsigned*)&h2;
        }
        const auto s02 = __builtin_amdgcn_permlane32_swap(a[0], a[2], false, false);
        const auto s13 = __builtin_amdgcn_permlane32_swap(a[1], a[3], false, false);
        const auto s46 = __builtin_amdgcn_permlane32_swap(a[4], a[6], false, false);
        const auto s57 = __builtin_amdgcn_permlane32_swap(a[5], a[7], false, false);

        U4 P0, P1;
        P0.u[0] = s02[0]; P0.u[1] = s13[0]; P0.u[2] = s02[1]; P0.u[3] = s13[1];
        P1.u[0] = s46[0]; P1.u[1] = s57[0]; P1.u[2] = s46[1]; P1.u[3] = s57[1];

        const unsigned short* src = &s_h[sel * HBUFSZ];
        union U2x { short8 v; uint2 q[2]; } Ah;
        __builtin_amdgcn_s_setprio(1);
        #pragma unroll
        for (int ks = 0; ks < 2; ++ks) {
            const int ko = sub * 32 + ks * 16 + hh * 8;
            const short8 Pv = ks ? P1.v : P0.v;
            Ah.q[0] = *(const uint2*)&src[shrA + ko];
            Ah.q[1] = *(const uint2*)&src[shrA + ko + 4];
            acc0 = __builtin_amdgcn_mfma_f32_32x32x16_bf16(Ah.v, Pv, acc0, 0, 0, 0);
            Ah.q[0] = *(const uint2*)&src[shrB + ko];
            Ah.q[1] = *(const uint2*)&src[shrB + ko + 4];
            acc1 = __builtin_amdgcn_mfma_f32_32x32x16_bf16(Ah.v, Pv, acc1, 0, 0, 0);
        }
        __builtin_amdgcn_s_setprio(0);
    };

    uint4  hrA[4], hrB[4];
    short8 afA[4], afB[4];

    issueH(base, hrA);
    writeH(0, hrA);
    issueAf(base, afA);
    if (ITERS > 1) issueH(base + NT, hrB);

    #pragma unroll
    for (int it = 0; it < ITERS; ++it) {
        const int sel = it & 1;
        __syncthreads();
        if (it + 1 < ITERS) {
            if (sel) writeH(sel ^ 1, hrA); else writeH(sel ^ 1, hrB);
        }
        if (it + 2 < ITERS) {
            if (sel) issueH(base + (it + 2) * NT, hrB);
            else     issueH(base + (it + 2) * NT, hrA);
        }
        if (it + 1 < ITERS) {
            if (sel) issueAf(base + (it + 1) * NT, afA);
            else     issueAf(base + (it + 1) * NT, afB);
        }
        const short8 (&af)[4] = sel ? afB : afA;
        f32x16 s0 = scores(af[0]);
        f32x16 s1 = scores(af[1]);
        pvstep(s0, 0, sel);
        f32x16 s2 = scores(af[2]);
        pvstep(s1, 1, sel);
        f32x16 s3 = scores(af[3]);
        pvstep(s2, 2, sel);
        pvstep(s3, 3, sel);
    }

    const float lsum = lsA + lsB;
    const float ltot = lsum + __shfl_xor(lsum, 32);
    if (hh == 0) l_part[(s * BATCH + b) * NSEQ + m] = ltot;

    unsigned short* ob = o_part + (size_t)(s * BATCH + b) * CDIM * NSEQ;
    #pragma unroll
    for (int r = 0; r < 16; ++r) {
        const int c0 = (r & 3) + 8 * (r >> 2) + 4 * hh;
        ob[(size_t)c0 * NSEQ + m]        = f2bf(acc0[r]);
        ob[(size_t)(32 + c0) * NSEQ + m] = f2bf(acc1[r]);
    }
}

// -------------------------------------------------------------------------
// Kernel 3: out = gamma * (sum_s o_part) / (sum_s l_part) + x
// Vectorized: 8 elements/thread, uint4 bf16 loads (G13).
// -------------------------------------------------------------------------
__global__ __launch_bounds__(256) void final_kernel(
    const float* __restrict__ x, const unsigned short* __restrict__ o_part,
    const float* __restrict__ l_part, const float* __restrict__ gamma,
    float* __restrict__ out)
{
    const size_t i = (size_t)(blockIdx.x * 256 + threadIdx.x) * 8;
    const int m = (int)(i & (NSEQ - 1));          // 8-aligned, same row b,c
    const int b = (int)(i >> 18);

    float o[8] = {0.f,0.f,0.f,0.f,0.f,0.f,0.f,0.f};
    float l[8] = {0.f,0.f,0.f,0.f,0.f,0.f,0.f,0.f};
    #pragma unroll
    for (int s = 0; s < NSPLIT; ++s) {
        const uint4 ov = *(const uint4*)&o_part[(size_t)s * (BATCH * CDIM * NSEQ) + i];
        const unsigned short* os = (const unsigned short*)&ov;
        #pragma unroll
        for (int j = 0; j < 8; ++j) o[j] += bf2f(os[j]);
        const float* lp = &l_part[s * (BATCH * NSEQ) + b * NSEQ + m];
        const float4 l0 = *(const float4*)&lp[0];
        const float4 l1 = *(const float4*)&lp[4];
        l[0] += l0.x; l[1] += l0.y; l[2] += l0.z; l[3] += l0.w;
        l[4] += l1.x; l[5] += l1.y; l[6] += l1.z; l[7] += l1.w;
    }
    const float g = gamma[0];
    const float4 x0 = *(const float4*)&x[i];
    const float4 x1 = *(const float4*)&x[i + 4];
    float4 o0, o1;
    o0.x = g * o[0] / l[0] + x0.x;  o0.y = g * o[1] / l[1] + x0.y;
    o0.z = g * o[2] / l[2] + x0.z;  o0.w = g * o[3] / l[3] + x0.w;
    o1.x = g * o[4] / l[4] + x1.x;  o1.y = g * o[5] / l[5] + x1.y;
    o1.z = g * o[6] / l[6] + x1.z;  o1.w = g * o[7] / l[7] + x1.w;
    *(float4*)&out[i]     = o0;
    *(float4*)&out[i + 4] = o1;
}

extern "C" void kernel_launch(void* const* d_in, const int* in_sizes, int n_in,
                              void* d_out, int out_size, void* d_ws, size_t ws_size,
                              hipStream_t stream) {
    const float* x     = (const float*)d_in[0];
    const float* wq    = (const float*)d_in[1];
    const float* wk    = (const float*)d_in[2];
    const float* wv    = (const float*)d_in[3];
    const float* gamma = (const float*)d_in[4];
    float* out = (float*)d_out;

    char* wsb = (char*)d_ws;
    unsigned short* f_pair = (unsigned short*)wsb;                         // 512 KB
    unsigned short* g_pair = f_pair + (size_t)BATCH * NSEQ * 16;           // 512 KB
    unsigned short* h_bf   = g_pair + (size_t)BATCH * NSEQ * 16;           // 2 MB
    unsigned short* o_part = (unsigned short*)(wsb + 3u * 1024 * 1024);    // 16 MB (bf16)
    float* l_part = (float*)(wsb + 19u * 1024 * 1024);                     // 512 KB

    hipLaunchKernelGGL(fgh_kernel, dim3(256), dim3(256), 0, stream,
                       x, wq, wk, wv, f_pair, g_pair, h_bf);
    hipLaunchKernelGGL(attn_kernel, dim3(BATCH * 32 * NSPLIT), dim3(256), 0, stream,
                       f_pair, g_pair, h_bf, o_part, l_part);
    hipLaunchKernelGGL(final_kernel, dim3((BATCH * CDIM * NSEQ) / (256 * 8)), dim3(256), 0, stream,
                       x, o_part, l_part, gamma, out);
}

// Round 8
// 45.269 us; speedup vs baseline: 1.6623x; 1.0623x over previous
//
#include <hip/hip_runtime.h>
#include <hip/hip_bf16.h>
#include <cmath>

#define BATCH  4
#define CDIM   64
#define CK     8
#define NSEQ   4096
#define NSPLIT 8
#define MT     128                    // m per block: 4 waves x 32
#define NT     128                    // n per staged h tile
#define NCHUNK (NSEQ / NSPLIT)        // 512 n per block
#define ITERS  (NCHUNK / NT)          // 4
#define HSTR   132                    // s_h row stride in shorts (264B, b64 2-way-free)
#define HBUFSZ (CDIM * HSTR)
#define XP     72                     // h_kernel x-tile row stride in shorts (144B, 16B-aligned)
#define LOG2E  1.4426950408889634f

typedef __attribute__((ext_vector_type(8)))  short short8;
typedef __attribute__((ext_vector_type(16))) float f32x16;

__device__ inline unsigned short f2bf(float f) {
    union { float f; unsigned u; } v; v.f = f;
    unsigned r = v.u + 0x7fff + ((v.u >> 16) & 1);   // RNE
    return (unsigned short)(r >> 16);
}
__device__ inline float bf2f(unsigned short h) {
    union { unsigned u; float f; } v; v.u = ((unsigned)h) << 16;
    return v.f;
}

// -------------------------------------------------------------------------
// Kernel 1a: f = wq@x, g = wk@x (pre-scaled by log2e). fp32 VALU.
// 512 blocks x 256 threads; block = 32 n of one batch. Octet split o = t&7
// with per-octet ROTATED c visit order c = 8o + ((ci+o)&7):
// wq/wk rows padded to 12 floats -> bank starts 12cc mod 32 =
// {0,12,24,4,16,28,8,20} distinct per octet -> b128 reads tile all 32 banks.
// -------------------------------------------------------------------------
__global__ __launch_bounds__(256) void fg_kernel(
    const float* __restrict__ x,  const float* __restrict__ wq,
    const float* __restrict__ wk,
    unsigned short* __restrict__ f_pair, unsigned short* __restrict__ g_pair)
{
    __shared__ __align__(16) float s_wq[CDIM][12];
    __shared__ __align__(16) float s_wk[CDIM][12];

    const int t = threadIdx.x;
    #pragma unroll
    for (int u = 0; u < 2; ++u) {
        const int i = t + u * 256;        // 512 = 8k x 64c
        const int k = i >> 6, c = i & 63;
        s_wq[c][k] = wq[i];
        s_wk[c][k] = wk[i];
    }
    __syncthreads();

    const int b  = blockIdx.x >> 7;           // 512 = 4b x 128 chunks
    const int n0 = (blockIdx.x & 127) * 32;
    const int nl = t >> 3;                    // 0..31
    const int o  = t & 7;                     // c-octet
    const int n  = n0 + nl;

    float fa[CK] = {0.f};
    float ga[CK] = {0.f};

    #pragma unroll
    for (int ci = 0; ci < 8; ++ci) {
        const int c   = 8 * o + ((ci + o) & 7);   // rotated visit order
        const float xv = x[(b * CDIM + c) * NSEQ + n];

        const float4 q0 = *(const float4*)&s_wq[c][0];
        const float4 q1 = *(const float4*)&s_wq[c][4];
        fa[0] += q0.x * xv; fa[1] += q0.y * xv; fa[2] += q0.z * xv; fa[3] += q0.w * xv;
        fa[4] += q1.x * xv; fa[5] += q1.y * xv; fa[6] += q1.z * xv; fa[7] += q1.w * xv;

        const float4 k0  = *(const float4*)&s_wk[c][0];
        const float4 k1v = *(const float4*)&s_wk[c][4];
        ga[0] += k0.x * xv; ga[1] += k0.y * xv; ga[2] += k0.z * xv; ga[3] += k0.w * xv;
        ga[4] += k1v.x * xv; ga[5] += k1v.y * xv; ga[6] += k1v.z * xv; ga[7] += k1v.w * xv;
    }

    // reduce across the 8-lane octet group (adjacent lanes)
    #pragma unroll
    for (int k = 0; k < CK; ++k) {
        fa[k] += __shfl_xor(fa[k], 1); fa[k] += __shfl_xor(fa[k], 2); fa[k] += __shfl_xor(fa[k], 4);
        ga[k] += __shfl_xor(ga[k], 1); ga[k] += __shfl_xor(ga[k], 2); ga[k] += __shfl_xor(ga[k], 4);
    }

    if (o == 0) {
        unsigned short buf[16];
        #pragma unroll
        for (int k = 0; k < CK; ++k) {
            buf[k]     = f2bf(fa[k]);
            buf[8 + k] = f2bf(fa[k] - bf2f(buf[k]));
        }
        uint4* dst = (uint4*)&f_pair[(size_t)(b * NSEQ + n) * 16];
        dst[0] = ((const uint4*)buf)[0];
        dst[1] = ((const uint4*)buf)[1];
    }
    if (o == 1) {
        unsigned short buf[16];
        #pragma unroll
        for (int k = 0; k < CK; ++k) {
            const float gs = ga[k] * LOG2E;          // fold log2e into scores
            buf[k]     = f2bf(gs);
            buf[8 + k] = f2bf(gs - bf2f(buf[k]));
        }
        uint4* dst = (uint4*)&g_pair[(size_t)(b * NSEQ + n) * 16];
        dst[0] = ((const uint4*)buf)[0];
        dst[1] = ((const uint4*)buf)[1];
    }
}

// -------------------------------------------------------------------------
// Kernel 1b: h = wv@x via MFMA. 512 blocks x 64 threads (1 wave, 32-n tile).
// wv held in registers as split-bf16 (hi+lo => fp32-accurate weights);
// x tile staged transposed [n][c] bf16 in LDS; B-frags = b128 row reads;
// C/D write = attn's proven o_part pattern. D = (wv_hi + wv_lo) @ x_bf.
// -------------------------------------------------------------------------
__global__ __launch_bounds__(64) void h_kernel(
    const float* __restrict__ x, const float* __restrict__ wv,
    unsigned short* __restrict__ h_bf)
{
    __shared__ __align__(16) unsigned short s_xt[32][XP];   // [n][c] bf16

    const int lane = threadIdx.x;
    const int hh   = lane >> 5;
    const int lm   = lane & 31;

    const int bid = blockIdx.x;            // 512 = b(4) x 128 n-tiles
    const int b   = bid >> 7;
    const int n0  = (bid & 127) * 32;

    // wv A-frags: [mtile][kc], row = mt*32+lm, k = kc*16 + hh*8 + j
    union U4 { short8 v; unsigned short us[8]; };
    U4 Avh[2][4], Avl[2][4];
    #pragma unroll
    for (int mt2 = 0; mt2 < 2; ++mt2) {
        const int row = mt2 * 32 + lm;
        #pragma unroll
        for (int kc = 0; kc < 4; ++kc) {
            const int k0 = kc * 16 + hh * 8;
            const float4 w0 = *(const float4*)&wv[row * 64 + k0];
            const float4 w1 = *(const float4*)&wv[row * 64 + k0 + 4];
            const float wf[8] = {w0.x, w0.y, w0.z, w0.w, w1.x, w1.y, w1.z, w1.w};
            #pragma unroll
            for (int j = 0; j < 8; ++j) {
                const unsigned short hi = f2bf(wf[j]);
                Avh[mt2][kc].us[j] = hi;
                Avl[mt2][kc].us[j] = f2bf(wf[j] - bf2f(hi));
            }
        }
    }

    // stage x tile transposed: lane owns row c = lane; 32 n as 8 float4
    {
        const float* xs = &x[(size_t)(b * CDIM + lane) * NSEQ + n0];
        #pragma unroll
        for (int u = 0; u < 8; ++u) {
            const float4 v = *(const float4*)&xs[u * 4];
            s_xt[u*4 + 0][lane] = f2bf(v.x);
            s_xt[u*4 + 1][lane] = f2bf(v.y);
            s_xt[u*4 + 2][lane] = f2bf(v.z);
            s_xt[u*4 + 3][lane] = f2bf(v.w);
        }
    }
    __syncthreads();

    f32x16 acc0 = {}, acc1 = {};
    #pragma unroll
    for (int kc = 0; kc < 4; ++kc) {
        union U2x { short8 v; uint2 q[2]; } Bx;
        Bx.q[0] = *(const uint2*)&s_xt[lm][kc * 16 + hh * 8];
        Bx.q[1] = *(const uint2*)&s_xt[lm][kc * 16 + hh * 8 + 4];
        acc0 = __builtin_amdgcn_mfma_f32_32x32x16_bf16(Avh[0][kc].v, Bx.v, acc0, 0, 0, 0);
        acc0 = __builtin_amdgcn_mfma_f32_32x32x16_bf16(Avl[0][kc].v, Bx.v, acc0, 0, 0, 0);
        acc1 = __builtin_amdgcn_mfma_f32_32x32x16_bf16(Avh[1][kc].v, Bx.v, acc1, 0, 0, 0);
        acc1 = __builtin_amdgcn_mfma_f32_32x32x16_bf16(Avl[1][kc].v, Bx.v, acc1, 0, 0, 0);
    }

    unsigned short* hb = h_bf + (size_t)b * CDIM * NSEQ;
    #pragma unroll
    for (int r = 0; r < 16; ++r) {
        const int c0 = (r & 3) + 8 * (r >> 2) + 4 * hh;
        hb[(size_t)c0 * NSEQ + n0 + lm]        = f2bf(acc0[r]);
        hb[(size_t)(32 + c0) * NSEQ + n0 + lm] = f2bf(acc1[r]);
    }
}

// -------------------------------------------------------------------------
// Kernel 2 (UNCHANGED from round 6/7): all-MFMA flash attention.
// -------------------------------------------------------------------------
__global__ __launch_bounds__(256, 4) void attn_kernel(
    const unsigned short* __restrict__ f_pair,
    const unsigned short* __restrict__ g_pair,
    const unsigned short* __restrict__ h_bf,
    unsigned short* __restrict__ o_part, float* __restrict__ l_part)
{
    __shared__ __align__(16) unsigned short s_h[2 * HBUFSZ];

    const int t    = threadIdx.x;
    const int lane = t & 63;
    const int w    = t >> 6;
    const int hh   = lane >> 5;
    const int lm   = lane & 31;

    const int bid = blockIdx.x;          // 1024 = s(8) * mt(32) * b(4)
    const int s   = bid & (NSPLIT - 1);
    const int mt  = (bid >> 3) & 31;
    const int b   = bid >> 8;

    const int m = mt * MT + w * 32 + lm;

    union U4 { short8 v; uint4 q4; unsigned u[4]; };

    U4 Bgh, Bgl;
    {
        const uint4* gp = (const uint4*)&g_pair[(size_t)(b * NSEQ + m) * 16];
        Bgh.q4 = gp[0];
        Bgl.q4 = gp[1];
    }

    f32x16 acc0 = {}, acc1 = {};
    const f32x16 kZero = {};
    float lsA = 0.f, lsB = 0.f;

    const unsigned short* fp = f_pair + (size_t)b * NSEQ * 16;
    const unsigned short* hb = h_bf  + (size_t)b * CDIM * NSEQ;
    const int base = s * NCHUNK;

    const int c_lo  = t >> 4;
    const int ng_st = t & 15;
    const unsigned short* fpl = fp + (size_t)lm * 16 + hh * 8;
    const unsigned short* hbl = hb + (size_t)c_lo * NSEQ + ng_st * 8;
    const int shw  = c_lo * HSTR + ng_st * 8;
    const int shrA = lm * HSTR;
    const int shrB = (32 + lm) * HSTR;

    auto issueH = [&](int n0, uint4 (&hr)[4]) {
        #pragma unroll
        for (int u = 0; u < 4; ++u)
            hr[u] = *(const uint4*)&hbl[(size_t)u * 16 * NSEQ + n0];
    };
    auto writeH = [&](int sel, const uint4 (&hr)[4]) {
        unsigned short* dst = &s_h[sel * HBUFSZ];
        #pragma unroll
        for (int u = 0; u < 4; ++u) {
            *(uint2*)&dst[shw + u * 16 * HSTR]     = make_uint2(hr[u].x, hr[u].y);
            *(uint2*)&dst[shw + u * 16 * HSTR + 4] = make_uint2(hr[u].z, hr[u].w);
        }
    };
    auto issueAf = [&](int n0, short8 (&af)[4]) {
        const unsigned short* p = fpl + (size_t)n0 * 16;
        #pragma unroll
        for (int sub = 0; sub < 4; ++sub)
            af[sub] = *(const short8*)&p[sub * 32 * 16];
    };
    auto scores = [&](const short8& a) -> f32x16 {
        f32x16 sc = __builtin_amdgcn_mfma_f32_32x32x16_bf16(a, Bgh.v, kZero, 0, 0, 0);
        return   __builtin_amdgcn_mfma_f32_32x32x16_bf16(a, Bgl.v, sc, 0, 0, 0);
    };
    auto pvstep = [&](const f32x16& sc, int sub, int sel) {
        unsigned a[8];
        #pragma unroll
        for (int p = 0; p < 8; ++p) {
            const float e0 = __builtin_amdgcn_exp2f(sc[2*p]);
            const float e1 = __builtin_amdgcn_exp2f(sc[2*p+1]);
            lsA += e0; lsB += e1;
            __hip_bfloat162 h2 = __float22bfloat162_rn(make_float2(e0, e1));
            a[p] = *(unsigned*)&h2;
        }
        const auto s02 = __builtin_amdgcn_permlane32_swap(a[0], a[2], false, false);
        const auto s13 = __builtin_amdgcn_permlane32_swap(a[1], a[3], false, false);
        const auto s46 = __builtin_amdgcn_permlane32_swap(a[4], a[6], false, false);
        const auto s57 = __builtin_amdgcn_permlane32_swap(a[5], a[7], false, false);

        U4 P0, P1;
        P0.u[0] = s02[0]; P0.u[1] = s13[0]; P0.u[2] = s02[1]; P0.u[3] = s13[1];
        P1.u[0] = s46[0]; P1.u[1] = s57[0]; P1.u[2] = s46[1]; P1.u[3] = s57[1];

        const unsigned short* src = &s_h[sel * HBUFSZ];
        union U2x { short8 v; uint2 q[2]; } Ah;
        __builtin_amdgcn_s_setprio(1);
        #pragma unroll
        for (int ks = 0; ks < 2; ++ks) {
            const int ko = sub * 32 + ks * 16 + hh * 8;
            const short8 Pv = ks ? P1.v : P0.v;
            Ah.q[0] = *(const uint2*)&src[shrA + ko];
            Ah.q[1] = *(const uint2*)&src[shrA + ko + 4];
            acc0 = __builtin_amdgcn_mfma_f32_32x32x16_bf16(Ah.v, Pv, acc0, 0, 0, 0);
            Ah.q[0] = *(const uint2*)&src[shrB + ko];
            Ah.q[1] = *(const uint2*)&src[shrB + ko + 4];
            acc1 = __builtin_amdgcn_mfma_f32_32x32x16_bf16(Ah.v, Pv, acc1, 0, 0, 0);
        }
        __builtin_amdgcn_s_setprio(0);
    };

    uint4  hrA[4], hrB[4];
    short8 afA[4], afB[4];

    issueH(base, hrA);
    writeH(0, hrA);
    issueAf(base, afA);
    if (ITERS > 1) issueH(base + NT, hrB);

    #pragma unroll
    for (int it = 0; it < ITERS; ++it) {
        const int sel = it & 1;
        __syncthreads();
        if (it + 1 < ITERS) {
            if (sel) writeH(sel ^ 1, hrA); else writeH(sel ^ 1, hrB);
        }
        if (it + 2 < ITERS) {
            if (sel) issueH(base + (it + 2) * NT, hrB);
            else     issueH(base + (it + 2) * NT, hrA);
        }
        if (it + 1 < ITERS) {
            if (sel) issueAf(base + (it + 1) * NT, afA);
            else     issueAf(base + (it + 1) * NT, afB);
        }
        const short8 (&af)[4] = sel ? afB : afA;
        f32x16 s0 = scores(af[0]);
        f32x16 s1 = scores(af[1]);
        pvstep(s0, 0, sel);
        f32x16 s2 = scores(af[2]);
        pvstep(s1, 1, sel);
        f32x16 s3 = scores(af[3]);
        pvstep(s2, 2, sel);
        pvstep(s3, 3, sel);
    }

    const float lsum = lsA + lsB;
    const float ltot = lsum + __shfl_xor(lsum, 32);
    if (hh == 0) l_part[(s * BATCH + b) * NSEQ + m] = ltot;

    unsigned short* ob = o_part + (size_t)(s * BATCH + b) * CDIM * NSEQ;
    #pragma unroll
    for (int r = 0; r < 16; ++r) {
        const int c0 = (r & 3) + 8 * (r >> 2) + 4 * hh;
        ob[(size_t)c0 * NSEQ + m]        = f2bf(acc0[r]);
        ob[(size_t)(32 + c0) * NSEQ + m] = f2bf(acc1[r]);
    }
}

// -------------------------------------------------------------------------
// Kernel 3 (unchanged): out = gamma * (sum_s o_part) / (sum_s l_part) + x
// -------------------------------------------------------------------------
__global__ __launch_bounds__(256) void final_kernel(
    const float* __restrict__ x, const unsigned short* __restrict__ o_part,
    const float* __restrict__ l_part, const float* __restrict__ gamma,
    float* __restrict__ out)
{
    const size_t i = (size_t)(blockIdx.x * 256 + threadIdx.x) * 8;
    const int m = (int)(i & (NSEQ - 1));
    const int b = (int)(i >> 18);

    float o[8] = {0.f,0.f,0.f,0.f,0.f,0.f,0.f,0.f};
    float l[8] = {0.f,0.f,0.f,0.f,0.f,0.f,0.f,0.f};
    #pragma unroll
    for (int s = 0; s < NSPLIT; ++s) {
        const uint4 ov = *(const uint4*)&o_part[(size_t)s * (BATCH * CDIM * NSEQ) + i];
        const unsigned short* os = (const unsigned short*)&ov;
        #pragma unroll
        for (int j = 0; j < 8; ++j) o[j] += bf2f(os[j]);
        const float* lp = &l_part[s * (BATCH * NSEQ) + b * NSEQ + m];
        const float4 l0 = *(const float4*)&lp[0];
        const float4 l1 = *(const float4*)&lp[4];
        l[0] += l0.x; l[1] += l0.y; l[2] += l0.z; l[3] += l0.w;
        l[4] += l1.x; l[5] += l1.y; l[6] += l1.z; l[7] += l1.w;
    }
    const float g = gamma[0];
    const float4 x0 = *(const float4*)&x[i];
    const float4 x1 = *(const float4*)&x[i + 4];
    float4 o0, o1;
    o0.x = g * o[0] / l[0] + x0.x;  o0.y = g * o[1] / l[1] + x0.y;
    o0.z = g * o[2] / l[2] + x0.z;  o0.w = g * o[3] / l[3] + x0.w;
    o1.x = g * o[4] / l[4] + x1.x;  o1.y = g * o[5] / l[5] + x1.y;
    o1.z = g * o[6] / l[6] + x1.z;  o1.w = g * o[7] / l[7] + x1.w;
    *(float4*)&out[i]     = o0;
    *(float4*)&out[i + 4] = o1;
}

extern "C" void kernel_launch(void* const* d_in, const int* in_sizes, int n_in,
                              void* d_out, int out_size, void* d_ws, size_t ws_size,
                              hipStream_t stream) {
    const float* x     = (const float*)d_in[0];
    const float* wq    = (const float*)d_in[1];
    const float* wk    = (const float*)d_in[2];
    const float* wv    = (const float*)d_in[3];
    const float* gamma = (const float*)d_in[4];
    float* out = (float*)d_out;

    char* wsb = (char*)d_ws;
    unsigned short* f_pair = (unsigned short*)wsb;                         // 512 KB
    unsigned short* g_pair = f_pair + (size_t)BATCH * NSEQ * 16;           // 512 KB
    unsigned short* h_bf   = g_pair + (size_t)BATCH * NSEQ * 16;           // 2 MB
    unsigned short* o_part = (unsigned short*)(wsb + 3u * 1024 * 1024);    // 16 MB (bf16)
    float* l_part = (float*)(wsb + 19u * 1024 * 1024);                     // 512 KB

    hipLaunchKernelGGL(fg_kernel, dim3(512), dim3(256), 0, stream,
                       x, wq, wk, f_pair, g_pair);
    hipLaunchKernelGGL(h_kernel, dim3(512), dim3(64), 0, stream,
                       x, wv, h_bf);
    hipLaunchKernelGGL(attn_kernel, dim3(BATCH * 32 * NSPLIT), dim3(256), 0, stream,
                       f_pair, g_pair, h_bf, o_part, l_part);
    hipLaunchKernelGGL(final_kernel, dim3((BATCH * CDIM * NSEQ) / (256 * 8)), dim3(256), 0, stream,
                       x, o_part, l_part, gamma, out);
}

// Round 9
// 44.817 us; speedup vs baseline: 1.6791x; 1.0101x over previous
//
#include <hip/hip_runtime.h>
#include <hip/hip_bf16.h>
#include <cmath>

#define BATCH  4
#define CDIM   64
#define CK     8
#define NSEQ   4096
#define NSPLIT 8
#define NCHUNK (NSEQ / NSPLIT)        // 512 n per attn block
#define NSUBS  (NCHUNK / 32)          // 16 PV subs per block
#define LOG2E  1.4426950408889634f

typedef __attribute__((ext_vector_type(8)))  short short8;
typedef __attribute__((ext_vector_type(16))) float f32x16;

__device__ inline unsigned short f2bf(float f) {
    union { float f; unsigned u; } v; v.f = f;
    unsigned r = v.u + 0x7fff + ((v.u >> 16) & 1);   // RNE
    return (unsigned short)(r >> 16);
}
__device__ inline float bf2f(unsigned short h) {
    union { unsigned u; float f; } v; v.u = ((unsigned)h) << 16;
    return v.f;
}

// -------------------------------------------------------------------------
// Kernel 1a (unchanged from round 8): f = wq@x, g = wk@x (pre-scaled log2e).
// -------------------------------------------------------------------------
__global__ __launch_bounds__(256) void fg_kernel(
    const float* __restrict__ x,  const float* __restrict__ wq,
    const float* __restrict__ wk,
    unsigned short* __restrict__ f_pair, unsigned short* __restrict__ g_pair)
{
    __shared__ __align__(16) float s_wq[CDIM][12];
    __shared__ __align__(16) float s_wk[CDIM][12];

    const int t = threadIdx.x;
    #pragma unroll
    for (int u = 0; u < 2; ++u) {
        const int i = t + u * 256;
        const int k = i >> 6, c = i & 63;
        s_wq[c][k] = wq[i];
        s_wk[c][k] = wk[i];
    }
    __syncthreads();

    const int b  = blockIdx.x >> 7;
    const int n0 = (blockIdx.x & 127) * 32;
    const int nl = t >> 3;
    const int o  = t & 7;
    const int n  = n0 + nl;

    float fa[CK] = {0.f};
    float ga[CK] = {0.f};

    #pragma unroll
    for (int ci = 0; ci < 8; ++ci) {
        const int c   = 8 * o + ((ci + o) & 7);   // rotated: conflict-free
        const float xv = x[(b * CDIM + c) * NSEQ + n];

        const float4 q0 = *(const float4*)&s_wq[c][0];
        const float4 q1 = *(const float4*)&s_wq[c][4];
        fa[0] += q0.x * xv; fa[1] += q0.y * xv; fa[2] += q0.z * xv; fa[3] += q0.w * xv;
        fa[4] += q1.x * xv; fa[5] += q1.y * xv; fa[6] += q1.z * xv; fa[7] += q1.w * xv;

        const float4 k0  = *(const float4*)&s_wk[c][0];
        const float4 k1v = *(const float4*)&s_wk[c][4];
        ga[0] += k0.x * xv; ga[1] += k0.y * xv; ga[2] += k0.z * xv; ga[3] += k0.w * xv;
        ga[4] += k1v.x * xv; ga[5] += k1v.y * xv; ga[6] += k1v.z * xv; ga[7] += k1v.w * xv;
    }

    #pragma unroll
    for (int k = 0; k < CK; ++k) {
        fa[k] += __shfl_xor(fa[k], 1); fa[k] += __shfl_xor(fa[k], 2); fa[k] += __shfl_xor(fa[k], 4);
        ga[k] += __shfl_xor(ga[k], 1); ga[k] += __shfl_xor(ga[k], 2); ga[k] += __shfl_xor(ga[k], 4);
    }

    if (o == 0) {
        unsigned short buf[16];
        #pragma unroll
        for (int k = 0; k < CK; ++k) {
            buf[k]     = f2bf(fa[k]);
            buf[8 + k] = f2bf(fa[k] - bf2f(buf[k]));
        }
        uint4* dst = (uint4*)&f_pair[(size_t)(b * NSEQ + n) * 16];
        dst[0] = ((const uint4*)buf)[0];
        dst[1] = ((const uint4*)buf)[1];
    }
    if (o == 1) {
        unsigned short buf[16];
        #pragma unroll
        for (int k = 0; k < CK; ++k) {
            const float gs = ga[k] * LOG2E;
            buf[k]     = f2bf(gs);
            buf[8 + k] = f2bf(gs - bf2f(buf[k]));
        }
        uint4* dst = (uint4*)&g_pair[(size_t)(b * NSEQ + n) * 16];
        dst[0] = ((const uint4*)buf)[0];
        dst[1] = ((const uint4*)buf)[1];
    }
}

// -------------------------------------------------------------------------
// Kernel 1b: h = wv@x via MFMA, output in ATTN-FRAGMENT layout:
// h_t[b][n/16][c][n%16] bf16 -> a PV A-frag is one coalesced uint4 per lane.
// 512 blocks x 64 threads, wv in registers as split-bf16 (fp32-accurate).
// -------------------------------------------------------------------------
__global__ __launch_bounds__(64) void h_kernel(
    const float* __restrict__ x, const float* __restrict__ wv,
    unsigned short* __restrict__ h_t)
{
    __shared__ __align__(16) unsigned short s_xt[32][72];   // [n][c] bf16

    const int lane = threadIdx.x;
    const int hh   = lane >> 5;
    const int lm   = lane & 31;

    const int bid = blockIdx.x;            // 512 = b(4) x 128 n-tiles
    const int b   = bid >> 7;
    const int n0  = (bid & 127) * 32;

    union U4 { short8 v; unsigned short us[8]; };
    U4 Avh[2][4], Avl[2][4];
    #pragma unroll
    for (int mt2 = 0; mt2 < 2; ++mt2) {
        const int row = mt2 * 32 + lm;
        #pragma unroll
        for (int kc = 0; kc < 4; ++kc) {
            const int k0 = kc * 16 + hh * 8;
            const float4 w0 = *(const float4*)&wv[row * 64 + k0];
            const float4 w1 = *(const float4*)&wv[row * 64 + k0 + 4];
            const float wf[8] = {w0.x, w0.y, w0.z, w0.w, w1.x, w1.y, w1.z, w1.w};
            #pragma unroll
            for (int j = 0; j < 8; ++j) {
                const unsigned short hi = f2bf(wf[j]);
                Avh[mt2][kc].us[j] = hi;
                Avl[mt2][kc].us[j] = f2bf(wf[j] - bf2f(hi));
            }
        }
    }

    {
        const float* xs = &x[(size_t)(b * CDIM + lane) * NSEQ + n0];
        #pragma unroll
        for (int u = 0; u < 8; ++u) {
            const float4 v = *(const float4*)&xs[u * 4];
            s_xt[u*4 + 0][lane] = f2bf(v.x);
            s_xt[u*4 + 1][lane] = f2bf(v.y);
            s_xt[u*4 + 2][lane] = f2bf(v.z);
            s_xt[u*4 + 3][lane] = f2bf(v.w);
        }
    }
    __syncthreads();

    f32x16 acc0 = {}, acc1 = {};
    #pragma unroll
    for (int kc = 0; kc < 4; ++kc) {
        union U2x { short8 v; uint2 q[2]; } Bx;
        Bx.q[0] = *(const uint2*)&s_xt[lm][kc * 16 + hh * 8];
        Bx.q[1] = *(const uint2*)&s_xt[lm][kc * 16 + hh * 8 + 4];
        acc0 = __builtin_amdgcn_mfma_f32_32x32x16_bf16(Avh[0][kc].v, Bx.v, acc0, 0, 0, 0);
        acc0 = __builtin_amdgcn_mfma_f32_32x32x16_bf16(Avl[0][kc].v, Bx.v, acc0, 0, 0, 0);
        acc1 = __builtin_amdgcn_mfma_f32_32x32x16_bf16(Avh[1][kc].v, Bx.v, acc1, 0, 0, 0);
        acc1 = __builtin_amdgcn_mfma_f32_32x32x16_bf16(Avl[1][kc].v, Bx.v, acc1, 0, 0, 0);
    }

    // scatter into fragment layout: n = n0+lm -> block nb = n>>4, elem n&15
    unsigned short* htb = h_t + (size_t)(b * (NSEQ / 16)) * (CDIM * 16);
    const size_t nbase = (size_t)((n0 >> 4) + (lm >> 4)) * (CDIM * 16) + (lm & 15);
    #pragma unroll
    for (int r = 0; r < 16; ++r) {
        const int c0 = (r & 3) + 8 * (r >> 2) + 4 * hh;
        htb[nbase + (size_t)c0 * 16]        = f2bf(acc0[r]);
        htb[nbase + (size_t)(32 + c0) * 16] = f2bf(acc1[r]);
    }
}

// -------------------------------------------------------------------------
// Kernel 2: barrier-free, LDS-free MFMA flash attention. 4096 one-wave
// blocks (s = bid&7 -> per-XCD h-chunk L2 residency). Flat 16-sub register
// pipeline: j+2-ahead global prefetch of h-frags (uint4, coalesced via h_t
// layout) and f-frags; scores = exact split-bf16 MFMA pair; P exchanged
// in-register via permlane32_swap; no-max softmax; bf16 partial stores.
// -------------------------------------------------------------------------
__global__ __launch_bounds__(64, 4) void attn_kernel(
    const unsigned short* __restrict__ f_pair,
    const unsigned short* __restrict__ g_pair,
    const unsigned short* __restrict__ h_t,
    unsigned short* __restrict__ o_part, float* __restrict__ l_part)
{
    const int lane = threadIdx.x;
    const int hh   = lane >> 5;
    const int lm   = lane & 31;

    const int bid = blockIdx.x;          // 4096 = s(8) * mt(128) * b(4)
    const int s   = bid & (NSPLIT - 1);
    const int mt  = (bid >> 3) & 127;
    const int b   = bid >> 10;

    const int m = mt * 32 + lm;

    union U4 { short8 v; uint4 q4; unsigned u[4]; };

    U4 Bgh, Bgl;
    {
        const uint4* gp = (const uint4*)&g_pair[(size_t)(b * NSEQ + m) * 16];
        Bgh.q4 = gp[0];
        Bgl.q4 = gp[1];
    }

    f32x16 acc0 = {}, acc1 = {};
    const f32x16 kZero = {};
    float lsA = 0.f, lsB = 0.f;

    // f frags: + (s*NCHUNK + j*32)*16 per sub
    const unsigned short* fp = f_pair + (size_t)b * NSEQ * 16
                             + (size_t)lm * 16 + hh * 8;
    // h frags: chunk base (b, s), + ((j*2+ks)*64 + c)*16 per frag
    const unsigned short* ht = h_t + (size_t)(b * (NSEQ / 16) + s * (NCHUNK / 16)) * (CDIM * 16)
                             + hh * 8;

    auto loadAf = [&](int j) -> short8 {
        return *(const short8*)&fp[(size_t)(s * NCHUNK + j * 32) * 16];
    };
    auto loadH = [&](int j, uint4 (&ha)[2], uint4 (&hb2)[2]) {
        #pragma unroll
        for (int ks = 0; ks < 2; ++ks) {
            ha[ks]  = *(const uint4*)&ht[(size_t)((j * 2 + ks) * CDIM + lm) * 16];
            hb2[ks] = *(const uint4*)&ht[(size_t)((j * 2 + ks) * CDIM + 32 + lm) * 16];
        }
    };

    short8 af[2];
    uint4  hA[2][2], hB[2][2];

    af[0] = loadAf(0); loadH(0, hA[0], hB[0]);
    af[1] = loadAf(1); loadH(1, hA[1], hB[1]);

    #pragma unroll
    for (int j = 0; j < NSUBS; ++j) {
        const int cur = j & 1;

        // scores (exact fp32 via split-bf16 pair)
        f32x16 sc = __builtin_amdgcn_mfma_f32_32x32x16_bf16(af[cur], Bgh.v, kZero, 0, 0, 0);
        sc = __builtin_amdgcn_mfma_f32_32x32x16_bf16(af[cur], Bgl.v, sc, 0, 0, 0);

        // prefetch j+2 into this slot (consumed after PV below; compiler
        // renames regs, loads fly under exp/pack/PV + next iteration)
        if (j + 2 < NSUBS) af[cur] = loadAf(j + 2);

        unsigned a[8];
        #pragma unroll
        for (int p = 0; p < 8; ++p) {
            const float e0 = __builtin_amdgcn_exp2f(sc[2*p]);
            const float e1 = __builtin_amdgcn_exp2f(sc[2*p+1]);
            lsA += e0; lsB += e1;
            __hip_bfloat162 h2 = __float22bfloat162_rn(make_float2(e0, e1));
            a[p] = *(unsigned*)&h2;
        }
        const auto s02 = __builtin_amdgcn_permlane32_swap(a[0], a[2], false, false);
        const auto s13 = __builtin_amdgcn_permlane32_swap(a[1], a[3], false, false);
        const auto s46 = __builtin_amdgcn_permlane32_swap(a[4], a[6], false, false);
        const auto s57 = __builtin_amdgcn_permlane32_swap(a[5], a[7], false, false);

        U4 P0, P1;
        P0.u[0] = s02[0]; P0.u[1] = s13[0]; P0.u[2] = s02[1]; P0.u[3] = s13[1];
        P1.u[0] = s46[0]; P1.u[1] = s57[0]; P1.u[2] = s46[1]; P1.u[3] = s57[1];

        // PV: A-frags straight from registers (loaded from h_t)
        union U2x { short8 v; uint4 q; } Ax;
        __builtin_amdgcn_s_setprio(1);
        Ax.q = hA[cur][0];
        acc0 = __builtin_amdgcn_mfma_f32_32x32x16_bf16(Ax.v, P0.v, acc0, 0, 0, 0);
        Ax.q = hB[cur][0];
        acc1 = __builtin_amdgcn_mfma_f32_32x32x16_bf16(Ax.v, P0.v, acc1, 0, 0, 0);
        Ax.q = hA[cur][1];
        acc0 = __builtin_amdgcn_mfma_f32_32x32x16_bf16(Ax.v, P1.v, acc0, 0, 0, 0);
        Ax.q = hB[cur][1];
        acc1 = __builtin_amdgcn_mfma_f32_32x32x16_bf16(Ax.v, P1.v, acc1, 0, 0, 0);
        __builtin_amdgcn_s_setprio(0);

        if (j + 2 < NSUBS) loadH(j + 2, hA[cur], hB[cur]);
    }

    const float lsum = lsA + lsB;
    const float ltot = lsum + __shfl_xor(lsum, 32);
    if (hh == 0) l_part[(s * BATCH + b) * NSEQ + m] = ltot;

    unsigned short* ob = o_part + (size_t)(s * BATCH + b) * CDIM * NSEQ;
    #pragma unroll
    for (int r = 0; r < 16; ++r) {
        const int c0 = (r & 3) + 8 * (r >> 2) + 4 * hh;
        ob[(size_t)c0 * NSEQ + m]        = f2bf(acc0[r]);
        ob[(size_t)(32 + c0) * NSEQ + m] = f2bf(acc1[r]);
    }
}

// -------------------------------------------------------------------------
// Kernel 3 (unchanged): out = gamma * (sum_s o_part) / (sum_s l_part) + x
// -------------------------------------------------------------------------
__global__ __launch_bounds__(256) void final_kernel(
    const float* __restrict__ x, const unsigned short* __restrict__ o_part,
    const float* __restrict__ l_part, const float* __restrict__ gamma,
    float* __restrict__ out)
{
    const size_t i = (size_t)(blockIdx.x * 256 + threadIdx.x) * 8;
    const int m = (int)(i & (NSEQ - 1));
    const int b = (int)(i >> 18);

    float o[8] = {0.f,0.f,0.f,0.f,0.f,0.f,0.f,0.f};
    float l[8] = {0.f,0.f,0.f,0.f,0.f,0.f,0.f,0.f};
    #pragma unroll
    for (int s = 0; s < NSPLIT; ++s) {
        const uint4 ov = *(const uint4*)&o_part[(size_t)s * (BATCH * CDIM * NSEQ) + i];
        const unsigned short* os = (const unsigned short*)&ov;
        #pragma unroll
        for (int j = 0; j < 8; ++j) o[j] += bf2f(os[j]);
        const float* lp = &l_part[s * (BATCH * NSEQ) + b * NSEQ + m];
        const float4 l0 = *(const float4*)&lp[0];
        const float4 l1 = *(const float4*)&lp[4];
        l[0] += l0.x; l[1] += l0.y; l[2] += l0.z; l[3] += l0.w;
        l[4] += l1.x; l[5] += l1.y; l[6] += l1.z; l[7] += l1.w;
    }
    const float g = gamma[0];
    const float4 x0 = *(const float4*)&x[i];
    const float4 x1 = *(const float4*)&x[i + 4];
    float4 o0, o1;
    o0.x = g * o[0] / l[0] + x0.x;  o0.y = g * o[1] / l[1] + x0.y;
    o0.z = g * o[2] / l[2] + x0.z;  o0.w = g * o[3] / l[3] + x0.w;
    o1.x = g * o[4] / l[4] + x1.x;  o1.y = g * o[5] / l[5] + x1.y;
    o1.z = g * o[6] / l[6] + x1.z;  o1.w = g * o[7] / l[7] + x1.w;
    *(float4*)&out[i]     = o0;
    *(float4*)&out[i + 4] = o1;
}

extern "C" void kernel_launch(void* const* d_in, const int* in_sizes, int n_in,
                              void* d_out, int out_size, void* d_ws, size_t ws_size,
                              hipStream_t stream) {
    const float* x     = (const float*)d_in[0];
    const float* wq    = (const float*)d_in[1];
    const float* wk    = (const float*)d_in[2];
    const float* wv    = (const float*)d_in[3];
    const float* gamma = (const float*)d_in[4];
    float* out = (float*)d_out;

    char* wsb = (char*)d_ws;
    unsigned short* f_pair = (unsigned short*)wsb;                         // 512 KB
    unsigned short* g_pair = f_pair + (size_t)BATCH * NSEQ * 16;           // 512 KB
    unsigned short* h_t    = g_pair + (size_t)BATCH * NSEQ * 16;           // 2 MB
    unsigned short* o_part = (unsigned short*)(wsb + 3u * 1024 * 1024);    // 16 MB (bf16)
    float* l_part = (float*)(wsb + 19u * 1024 * 1024);                     // 512 KB

    hipLaunchKernelGGL(fg_kernel, dim3(512), dim3(256), 0, stream,
                       x, wq, wk, f_pair, g_pair);
    hipLaunchKernelGGL(h_kernel, dim3(512), dim3(64), 0, stream,
                       x, wv, h_t);
    hipLaunchKernelGGL(attn_kernel, dim3(BATCH * 128 * NSPLIT), dim3(64), 0, stream,
                       f_pair, g_pair, h_t, o_part, l_part);
    hipLaunchKernelGGL(final_kernel, dim3((BATCH * CDIM * NSEQ) / (256 * 8)), dim3(256), 0, stream,
                       x, o_part, l_part, gamma, out);
}